// Round 12
// baseline (300.783 us; speedup 1.0000x reference)
//
#include <hip/hip_runtime.h>
#include <hip/hip_fp16.h>
#include <math.h>

#define F_IN 128
#define HID  32

#define NPB   586      // nodes per bucket = ceil(150000/256) -> exactly 256 buckets
#define NBK   256      // bucket count (kept at 256: bpart scatter runs stay >= 1 line)
#define EPB   4688     // edges per block; 512 blocks = 2 blocks/CU = 32 waves (100% occ)
#define BLK_E 1024     // threads per block for all CSR kernels

#define XPAD  132      // 128 + 4: 16B-aligned row stride, conflict-free b128 reads

__device__ __forceinline__ void fma4(float4& a, float s, const float4& w) {
    a.x = fmaf(s, w.x, a.x);
    a.y = fmaf(s, w.y, a.y);
    a.z = fmaf(s, w.z, a.z);
    a.w = fmaf(s, w.w, a.w);
}

__device__ __forceinline__ void add4(float4& a, const float4& v) {
    a.x += v.x; a.y += v.y; a.z += v.z; a.w += v.w;
}

__device__ __forceinline__ float4 shx4(float4 v, int m) {
    float4 r;
    r.x = __shfl_xor(v.x, m);
    r.y = __shfl_xor(v.y, m);
    r.z = __shfl_xor(v.z, m);
    r.w = __shfl_xor(v.w, m);
    return r;
}

// fp16 quad load/store: 8B per lane, fp32 math everywhere else.
__device__ __forceinline__ float4 ldh4(const __half* p) {
    uint2 u = *(const uint2*)p;
    __half2 h0 = *(__half2*)&u.x;
    __half2 h1 = *(__half2*)&u.y;
    float2 f0 = __half22float2(h0);
    float2 f1 = __half22float2(h1);
    return make_float4(f0.x, f0.y, f1.x, f1.y);
}
__device__ __forceinline__ void sth4(__half* p, float4 v) {
    __half2 h0 = __floats2half2_rn(v.x, v.y);
    __half2 h1 = __floats2half2_rn(v.z, v.w);
    uint2 u;
    u.x = *(unsigned*)&h0;
    u.y = *(unsigned*)&h1;
    *(uint2*)p = u;
}

// ================= binned CSR build =================
// Round-12: occupancy step. Round-11 (+11us from exact-256 grids) proved
// the CSR build is latency/straggler-bound. 1024-thread blocks at 1/CU
// were 16 waves = 50% occupancy; bhist/bpart now run 512 blocks = 2/CU
// = 32 waves = 100%. Scatter runs shrink 37->18 edges (73B, still >= one
// 64B line -- round-1's sub-line regression does not re-trigger).
// bcsr stays 256 blocks (block count pinned to nbuckets; more buckets
// would push bpart runs sub-line).

__global__ __launch_bounds__(BLK_E) void k_bhist(const int* __restrict__ dst,
                                                 int* __restrict__ bin_hist,
                                                 int* __restrict__ hb,
                                                 int e, int nbuckets) {
    __shared__ int h[NBK];
    int tid = threadIdx.x;
    if (tid < nbuckets) h[tid] = 0;
    __syncthreads();
    int base = blockIdx.x * EPB;
    if (base + EPB <= e) {
        const int4* d4 = (const int4*)(dst + base);
        for (int i = tid; i < EPB / 4; i += BLK_E) {
            int4 v = d4[i];
            atomicAdd(&h[v.x / NPB], 1);
            atomicAdd(&h[v.y / NPB], 1);
            atomicAdd(&h[v.z / NPB], 1);
            atomicAdd(&h[v.w / NPB], 1);
        }
    } else {
        for (int i = base + tid; i < e; i += BLK_E)
            atomicAdd(&h[dst[i] / NPB], 1);
    }
    __syncthreads();
    int hbase = blockIdx.x * nbuckets;
    if (tid < nbuckets) {
        int c = h[tid];
        if (c) atomicAdd(&bin_hist[tid], c);
        hb[hbase + tid] = c;
    }
}

#define BP_ONE(S, D) { \
    int b_ = (D) / NPB; int dl_ = (D) - b_ * NPB; \
    int r_ = atomicAdd(&lc[b_], 1); \
    tmp[h[b_] + r_] = (unsigned)(S) | ((unsigned)dl_ << 18); }

__global__ __launch_bounds__(BLK_E) void k_bpart(const int* __restrict__ src,
                                                 const int* __restrict__ dst,
                                                 const int* __restrict__ bin_hist,
                                                 int* __restrict__ bin_cur,
                                                 unsigned* __restrict__ tmp,
                                                 const int* __restrict__ hb,
                                                 int e, int nbuckets) {
    __shared__ int sh[BLK_E];
    __shared__ int h[NBK];
    __shared__ int lc[NBK];
    int t = threadIdx.x;
    // local scan of the global bucket histogram -> bin_off (replaces k_bscan)
    int hv = (t < nbuckets) ? bin_hist[t] : 0;
    sh[t] = hv; __syncthreads();
    for (int off = 1; off < BLK_E; off <<= 1) {
        int a = (t >= off) ? sh[t - off] : 0;
        __syncthreads();
        sh[t] += a;
        __syncthreads();
    }
    int hbase = blockIdx.x * nbuckets;
    if (t < nbuckets) {
        int boff = sh[t] - hv;                 // exclusive bucket offset
        int c = hb[hbase + t];                 // this block's count (from bhist)
        h[t] = c ? boff + atomicAdd(&bin_cur[t], c) : 0;   // absolute claim
        lc[t] = 0;
    }
    __syncthreads();
    int base = blockIdx.x * EPB;
    if (base + EPB <= e) {
        const int4* s4 = (const int4*)(src + base);
        const int4* d4 = (const int4*)(dst + base);
        for (int i = t; i < EPB / 4; i += BLK_E) {
            int4 sv = s4[i];
            int4 dv = d4[i];
            BP_ONE(sv.x, dv.x)
            BP_ONE(sv.y, dv.y)
            BP_ONE(sv.z, dv.z)
            BP_ONE(sv.w, dv.w)
        }
    } else {
        for (int i = base + t; i < e; i += BLK_E) {
            int d = dst[i];
            BP_ONE(src[i], d)
        }
    }
}
#undef BP_ONE

__global__ __launch_bounds__(BLK_E) void k_bcsr(const unsigned* __restrict__ tmp,
                                                const int* __restrict__ bin_hist,
                                                int* __restrict__ es,
                                                int* __restrict__ offsets,
                                                float* __restrict__ dis,
                                                int n, int nbuckets, int e) {
    __shared__ int sh[BLK_E];
    __shared__ int cnt[NPB];
    __shared__ int cur[NPB];
    __shared__ int sb[2];
    int b = blockIdx.x, t = threadIdx.x;
    // local scan of the bucket histogram -> this bucket's [s0, s1)
    int hv = (t < nbuckets) ? bin_hist[t] : 0;
    if (t < NPB) cnt[t] = 0;
    sh[t] = hv; __syncthreads();
    for (int off = 1; off < BLK_E; off <<= 1) {
        int a = (t >= off) ? sh[t - off] : 0;
        __syncthreads();
        sh[t] += a;
        __syncthreads();
    }
    if (t == b) { sb[0] = sh[t] - hv; sb[1] = sh[t]; }
    if (b == nbuckets - 1 && t == 0) offsets[n] = e;
    __syncthreads();
    int s0 = sb[0], s1 = sb[1];
    // count pass (uint4-vectorized: head / vector / tail)
    int a0 = (s0 + 3) & ~3; if (a0 > s1) a0 = s1;
    int a1 = s1 & ~3;       if (a1 < a0) a1 = a0;
    for (int i = s0 + t; i < a0; i += BLK_E)
        atomicAdd(&cnt[(tmp[i] >> 18) & 1023], 1);
    int nv = (a1 - a0) >> 2;
    const uint4* t4 = (const uint4*)(tmp + a0);
    for (int i = t; i < nv; i += BLK_E) {
        uint4 w = t4[i];
        atomicAdd(&cnt[(w.x >> 18) & 1023], 1);
        atomicAdd(&cnt[(w.y >> 18) & 1023], 1);
        atomicAdd(&cnt[(w.z >> 18) & 1023], 1);
        atomicAdd(&cnt[(w.w >> 18) & 1023], 1);
    }
    for (int i = a1 + t; i < s1; i += BLK_E)
        atomicAdd(&cnt[(tmp[i] >> 18) & 1023], 1);
    __syncthreads();
    // node prefix within the bucket
    int v = (t < NPB) ? cnt[t] : 0;
    sh[t] = v; __syncthreads();
    for (int off = 1; off < BLK_E; off <<= 1) {
        int a = (t >= off) ? sh[t - off] : 0;
        __syncthreads();
        sh[t] += a;
        __syncthreads();
    }
    if (t < NPB) {
        int excl = sh[t] - v;
        int node = b * NPB + t;
        if (node < n) {
            offsets[node] = s0 + excl;
            dis[node] = rsqrtf((float)(v + 1));
        }
        cur[t] = excl;
    }
    __syncthreads();
    // scatter pass (uint4-vectorized)
    for (int i = s0 + t; i < a0; i += BLK_E) {
        unsigned w = tmp[i];
        int dl = (w >> 18) & 1023;
        int r = atomicAdd(&cur[dl], 1);
        es[s0 + r] = (int)(w & 0x3FFFFu);
    }
    for (int i = t; i < nv; i += BLK_E) {
        uint4 w = t4[i];
        int d0 = (w.x >> 18) & 1023; int r0 = atomicAdd(&cur[d0], 1);
        es[s0 + r0] = (int)(w.x & 0x3FFFFu);
        int d1 = (w.y >> 18) & 1023; int r1 = atomicAdd(&cur[d1], 1);
        es[s0 + r1] = (int)(w.y & 0x3FFFFu);
        int d2 = (w.z >> 18) & 1023; int r2 = atomicAdd(&cur[d2], 1);
        es[s0 + r2] = (int)(w.z & 0x3FFFFu);
        int d3 = (w.w >> 18) & 1023; int r3 = atomicAdd(&cur[d3], 1);
        es[s0 + r3] = (int)(w.w & 0x3FFFFu);
    }
    for (int i = a1 + t; i < s1; i += BLK_E) {
        unsigned w = tmp[i];
        int dl = (w >> 18) & 1023;
        int r = atomicAdd(&cur[dl], 1);
        es[s0 + r] = (int)(w & 0x3FFFFu);
    }
}

// ================= transforms =================

// k_gemm1: x-tile bulk-staged in LDS (round 4); fp16 output (round 8).
__global__ __launch_bounds__(256) void k_gemm1(const float* __restrict__ x,
                                               const float* __restrict__ W,
                                               const float* __restrict__ dis,
                                               __half* __restrict__ u, int n) {
    __shared__ float Ws[F_IN * HID];   // 16 KB
    __shared__ float Xs[64 * XPAD];    // 33 KB
    int tid = threadIdx.x;
    for (int i = tid; i < F_IN * HID; i += 256) Ws[i] = W[i];
    int node0 = blockIdx.x * 64;
#pragma unroll
    for (int it = 0; it < 8; ++it) {
        int c  = it * 256 + tid;       // 2048 chunks of 16B
        int r  = c >> 5;               // 32 chunks per row
        int c4 = c & 31;
        int gr = node0 + r;
        if (gr >= n) gr = n - 1;       // in-bounds junk; outputs guarded
        float4 v = *(const float4*)&x[(size_t)gr * F_IN + c4 * 4];
        *(float4*)&Xs[r * XPAD + c4 * 4] = v;
    }
    int cg = tid & 7, gq = tid >> 3;
    float4 acc[2];
    acc[0] = make_float4(0.f, 0.f, 0.f, 0.f);
    acc[1] = make_float4(0.f, 0.f, 0.f, 0.f);
    __syncthreads();
#pragma unroll 4
    for (int ks = 0; ks < 32; ++ks) {
        float4 xv[2];
        xv[0] = *(const float4*)&Xs[gq * XPAD + ks * 4];
        xv[1] = *(const float4*)&Xs[(gq + 32) * XPAD + ks * 4];
        float4 w0 = *(const float4*)&Ws[(ks * 4 + 0) * HID + cg * 4];
        float4 w1 = *(const float4*)&Ws[(ks * 4 + 1) * HID + cg * 4];
        float4 w2 = *(const float4*)&Ws[(ks * 4 + 2) * HID + cg * 4];
        float4 w3 = *(const float4*)&Ws[(ks * 4 + 3) * HID + cg * 4];
#pragma unroll
        for (int m = 0; m < 2; ++m) {
            fma4(acc[m], xv[m].x, w0);
            fma4(acc[m], xv[m].y, w1);
            fma4(acc[m], xv[m].z, w2);
            fma4(acc[m], xv[m].w, w3);
        }
    }
#pragma unroll
    for (int m = 0; m < 2; ++m) {
        int node = node0 + gq + 32 * m;
        if (node < n) {
            float ds = dis[node];
            float4 r;
            r.x = acc[m].x * ds; r.y = acc[m].y * ds;
            r.z = acc[m].z * ds; r.w = acc[m].w * ds;
            sth4(&u[(size_t)node * HID + cg * 4], r);
        }
    }
}

// ================= gather aggregation =================
// Regime (rounds 5/7): per-CU outstanding-miss bound. fp16 node rows =
// one line per edge (round 8: confirmed). gemm2 fused via 8-lane
// butterfly allgather + LDS W2 matmul (round 7).

__global__ __launch_bounds__(256) void k_gather32_g2(const __half* __restrict__ uh,
                                                     const int* __restrict__ es,
                                                     const int* __restrict__ offsets,
                                                     const float* __restrict__ dis,
                                                     const float* __restrict__ b,
                                                     const float* __restrict__ W2,
                                                     __half* __restrict__ u2, int n) {
    __shared__ float Ws[HID * HID];   // 4 KB
    int tid = threadIdx.x;
    for (int i = tid; i < HID * HID; i += 256) Ws[i] = W2[i];
    __syncthreads();
    int t = blockIdx.x * 256 + tid;
    int node = t >> 3, q = t & 7;
    if (node >= n) return;
    int s0 = offsets[node];
    int s1 = offsets[node + 1];
    float4 acc = ldh4(&uh[(size_t)node * HID + q * 4]);   // self-loop
    int ei = s0;
    for (; ei + 8 <= s1; ei += 8) {
        int e0 = es[ei], e1 = es[ei + 1], e2 = es[ei + 2], e3 = es[ei + 3];
        int e4 = es[ei + 4], e5 = es[ei + 5], e6 = es[ei + 6], e7 = es[ei + 7];
        float4 v0 = ldh4(&uh[(size_t)e0 * HID + q * 4]);
        float4 v1 = ldh4(&uh[(size_t)e1 * HID + q * 4]);
        float4 v2 = ldh4(&uh[(size_t)e2 * HID + q * 4]);
        float4 v3 = ldh4(&uh[(size_t)e3 * HID + q * 4]);
        float4 v4 = ldh4(&uh[(size_t)e4 * HID + q * 4]);
        float4 v5 = ldh4(&uh[(size_t)e5 * HID + q * 4]);
        float4 v6 = ldh4(&uh[(size_t)e6 * HID + q * 4]);
        float4 v7 = ldh4(&uh[(size_t)e7 * HID + q * 4]);
        acc.x += ((v0.x + v1.x) + (v2.x + v3.x)) + ((v4.x + v5.x) + (v6.x + v7.x));
        acc.y += ((v0.y + v1.y) + (v2.y + v3.y)) + ((v4.y + v5.y) + (v6.y + v7.y));
        acc.z += ((v0.z + v1.z) + (v2.z + v3.z)) + ((v4.z + v5.z) + (v6.z + v7.z));
        acc.w += ((v0.w + v1.w) + (v2.w + v3.w)) + ((v4.w + v5.w) + (v6.w + v7.w));
    }
    for (; ei + 4 <= s1; ei += 4) {
        int e0 = es[ei], e1 = es[ei + 1], e2 = es[ei + 2], e3 = es[ei + 3];
        float4 v0 = ldh4(&uh[(size_t)e0 * HID + q * 4]);
        float4 v1 = ldh4(&uh[(size_t)e1 * HID + q * 4]);
        float4 v2 = ldh4(&uh[(size_t)e2 * HID + q * 4]);
        float4 v3 = ldh4(&uh[(size_t)e3 * HID + q * 4]);
        acc.x += (v0.x + v1.x) + (v2.x + v3.x);
        acc.y += (v0.y + v1.y) + (v2.y + v3.y);
        acc.z += (v0.z + v1.z) + (v2.z + v3.z);
        acc.w += (v0.w + v1.w) + (v2.w + v3.w);
    }
    for (; ei < s1; ++ei) {
        int s = es[ei];
        float4 v = ldh4(&uh[(size_t)s * HID + q * 4]);
        add4(acc, v);
    }
    float ds = dis[node];
    float4 r;   // h quad, k-range [q*4, q*4+4)
    r.x = fmaxf(fmaf(ds, acc.x, b[q * 4 + 0]), 0.0f);
    r.y = fmaxf(fmaf(ds, acc.y, b[q * 4 + 1]), 0.0f);
    r.z = fmaxf(fmaf(ds, acc.z, b[q * 4 + 2]), 0.0f);
    r.w = fmaxf(fmaf(ds, acc.w, b[q * 4 + 3]), 0.0f);

    // --- butterfly allgather: H0..H7 = full h row in every lane ---
    float4 o1 = shx4(r, 1);
    float4 L0 = (q & 1) ? o1 : r;
    float4 L1 = (q & 1) ? r  : o1;
    float4 M0 = shx4(L0, 2);
    float4 M1 = shx4(L1, 2);
    float4 P0 = (q & 2) ? M0 : L0;
    float4 P1 = (q & 2) ? M1 : L1;
    float4 P2 = (q & 2) ? L0 : M0;
    float4 P3 = (q & 2) ? L1 : M1;
    float4 Q0 = shx4(P0, 4);
    float4 Q1 = shx4(P1, 4);
    float4 Q2 = shx4(P2, 4);
    float4 Q3 = shx4(P3, 4);
    float4 H0 = (q & 4) ? Q0 : P0;
    float4 H1 = (q & 4) ? Q1 : P1;
    float4 H2 = (q & 4) ? Q2 : P2;
    float4 H3 = (q & 4) ? Q3 : P3;
    float4 H4 = (q & 4) ? P0 : Q0;
    float4 H5 = (q & 4) ? P1 : Q1;
    float4 H6 = (q & 4) ? P2 : Q2;
    float4 H7 = (q & 4) ? P3 : Q3;

    // --- u2 quad q = (h @ W2)[q*4 .. q*4+3], scaled by ds ---
    float4 oacc = make_float4(0.f, 0.f, 0.f, 0.f);
#define G2_STEP(Hj, j) { \
    float4 w0 = *(const float4*)&Ws[((j) * 4 + 0) * HID + q * 4]; \
    float4 w1 = *(const float4*)&Ws[((j) * 4 + 1) * HID + q * 4]; \
    float4 w2 = *(const float4*)&Ws[((j) * 4 + 2) * HID + q * 4]; \
    float4 w3 = *(const float4*)&Ws[((j) * 4 + 3) * HID + q * 4]; \
    fma4(oacc, Hj.x, w0); fma4(oacc, Hj.y, w1); \
    fma4(oacc, Hj.z, w2); fma4(oacc, Hj.w, w3); }
    G2_STEP(H0, 0) G2_STEP(H1, 1) G2_STEP(H2, 2) G2_STEP(H3, 3)
    G2_STEP(H4, 4) G2_STEP(H5, 5) G2_STEP(H6, 6) G2_STEP(H7, 7)
#undef G2_STEP
    float4 w;
    w.x = oacc.x * ds; w.y = oacc.y * ds;
    w.z = oacc.z * ds; w.w = oacc.w * ds;
    sth4(&u2[(size_t)node * HID + q * 4], w);
}

__global__ __launch_bounds__(256) void k_gather32_dot(const __half* __restrict__ uh,
                                                      const int* __restrict__ es,
                                                      const int* __restrict__ offsets,
                                                      const float* __restrict__ dis,
                                                      const float* __restrict__ b,
                                                      const float* __restrict__ W3,
                                                      float* __restrict__ s, int n) {
    int t = blockIdx.x * 256 + threadIdx.x;
    int node = t >> 3, q = t & 7;
    if (node >= n) return;
    int s0 = offsets[node];
    int s1 = offsets[node + 1];
    float4 acc = ldh4(&uh[(size_t)node * HID + q * 4]);
    int ei = s0;
    for (; ei + 8 <= s1; ei += 8) {
        int e0 = es[ei], e1 = es[ei + 1], e2 = es[ei + 2], e3 = es[ei + 3];
        int e4 = es[ei + 4], e5 = es[ei + 5], e6 = es[ei + 6], e7 = es[ei + 7];
        float4 v0 = ldh4(&uh[(size_t)e0 * HID + q * 4]);
        float4 v1 = ldh4(&uh[(size_t)e1 * HID + q * 4]);
        float4 v2 = ldh4(&uh[(size_t)e2 * HID + q * 4]);
        float4 v3 = ldh4(&uh[(size_t)e3 * HID + q * 4]);
        float4 v4 = ldh4(&uh[(size_t)e4 * HID + q * 4]);
        float4 v5 = ldh4(&uh[(size_t)e5 * HID + q * 4]);
        float4 v6 = ldh4(&uh[(size_t)e6 * HID + q * 4]);
        float4 v7 = ldh4(&uh[(size_t)e7 * HID + q * 4]);
        acc.x += ((v0.x + v1.x) + (v2.x + v3.x)) + ((v4.x + v5.x) + (v6.x + v7.x));
        acc.y += ((v0.y + v1.y) + (v2.y + v3.y)) + ((v4.y + v5.y) + (v6.y + v7.y));
        acc.z += ((v0.z + v1.z) + (v2.z + v3.z)) + ((v4.z + v5.z) + (v6.z + v7.z));
        acc.w += ((v0.w + v1.w) + (v2.w + v3.w)) + ((v4.w + v5.w) + (v6.w + v7.w));
    }
    for (; ei + 4 <= s1; ei += 4) {
        int e0 = es[ei], e1 = es[ei + 1], e2 = es[ei + 2], e3 = es[ei + 3];
        float4 v0 = ldh4(&uh[(size_t)e0 * HID + q * 4]);
        float4 v1 = ldh4(&uh[(size_t)e1 * HID + q * 4]);
        float4 v2 = ldh4(&uh[(size_t)e2 * HID + q * 4]);
        float4 v3 = ldh4(&uh[(size_t)e3 * HID + q * 4]);
        acc.x += (v0.x + v1.x) + (v2.x + v3.x);
        acc.y += (v0.y + v1.y) + (v2.y + v3.y);
        acc.z += (v0.z + v1.z) + (v2.z + v3.z);
        acc.w += (v0.w + v1.w) + (v2.w + v3.w);
    }
    for (; ei < s1; ++ei) {
        int sc = es[ei];
        float4 v = ldh4(&uh[(size_t)sc * HID + q * 4]);
        add4(acc, v);
    }
    float ds = dis[node];
    float4 r;
    r.x = fmaxf(fmaf(ds, acc.x, b[q * 4 + 0]), 0.0f);
    r.y = fmaxf(fmaf(ds, acc.y, b[q * 4 + 1]), 0.0f);
    r.z = fmaxf(fmaf(ds, acc.z, b[q * 4 + 2]), 0.0f);
    r.w = fmaxf(fmaf(ds, acc.w, b[q * 4 + 3]), 0.0f);
    float p = r.x * W3[q * 4 + 0] + r.y * W3[q * 4 + 1]
            + r.z * W3[q * 4 + 2] + r.w * W3[q * 4 + 3];
    p += __shfl_down(p, 4, 8);
    p += __shfl_down(p, 2, 8);
    p += __shfl_down(p, 1, 8);
    if (q == 0) s[node] = p * ds;
}

__global__ void k_gather1(const float* __restrict__ sv, const int* __restrict__ es,
                          const int* __restrict__ offsets, const float* __restrict__ dis,
                          const float* __restrict__ b3, float* __restrict__ out, int n) {
    int d = blockIdx.x * 256 + threadIdx.x;
    if (d >= n) return;
    float acc = sv[d];
    int s0 = offsets[d], s1 = offsets[d + 1];
    int ei = s0;
    for (; ei + 4 <= s1; ei += 4) {
        float v0 = sv[es[ei]], v1 = sv[es[ei + 1]];
        float v2 = sv[es[ei + 2]], v3 = sv[es[ei + 3]];
        acc += (v0 + v1) + (v2 + v3);
    }
    for (; ei < s1; ++ei) acc += sv[es[ei]];
    float z = dis[d] * acc + b3[0];
    out[d] = 1.0f / (1.0f + expf(-z));
}

// ================= launch =================

extern "C" void kernel_launch(void* const* d_in, const int* in_sizes, int n_in,
                              void* d_out, int out_size, void* d_ws, size_t ws_size,
                              hipStream_t stream) {
    const float* x  = (const float*)d_in[0];
    const int*   ei = (const int*)d_in[1];
    const float* W1 = (const float*)d_in[2];
    const float* b1 = (const float*)d_in[3];
    const float* W2 = (const float*)d_in[4];
    const float* b2 = (const float*)d_in[5];
    const float* W3 = (const float*)d_in[6];
    const float* b3 = (const float*)d_in[7];
    float* out = (float*)d_out;

    int n = out_size;             // 150000
    int e = in_sizes[1] / 2;      // 2400000
    const int* src = ei;
    const int* dst = ei + e;

    int nbuckets = (n + NPB - 1) / NPB;   // 256
    int gEb      = (e + EPB - 1) / EPB;   // 512

    __half* A       = (__half*)d_ws;                // n*32 halfs (9.6MB)
    __half* B       = A + (size_t)n * HID;          // n*32 halfs (9.6MB; aliases tmp)
    float* dis      = (float*)(B + (size_t)n * HID);// n f
    float* Cs       = dis + n;                      // n f
    int*   offsets  = (int*)(Cs + n);               // n+1 i
    int*   es       = offsets + (n + 1);            // e i
    int*   bin_hist = es + e;                       // nbuckets i
    int*   bin_cur  = bin_hist + nbuckets;          // nbuckets i (adjacent: one memset)
    int*   hb       = bin_cur + nbuckets;           // gEb*nbuckets i (512KB)
    unsigned* tmp   = (unsigned*)B;                 // e u32 (9.6MB) == B size

    dim3 blk(256);
    int gN    = (n + 255) / 256;
    int gN8   = (n * 8 + 255) / 256;
    int g64   = (n + 63) / 64;         // 2344

    // ---- CSR build (bhist/bpart: 512 blocks = 2/CU = 32 waves; bcsr: 256) ----
    hipMemsetAsync(bin_hist, 0, (size_t)(2 * nbuckets) * sizeof(int), stream);
    k_bhist<<<gEb, dim3(BLK_E), 0, stream>>>(dst, bin_hist, hb, e, nbuckets);
    k_bpart<<<gEb, dim3(BLK_E), 0, stream>>>(src, dst, bin_hist, bin_cur, tmp, hb, e, nbuckets);
    k_bcsr <<<nbuckets, dim3(BLK_E), 0, stream>>>(tmp, bin_hist, es, offsets, dis, n, nbuckets, e);

    // ---- layer 1 (+ fused layer-2 transform) ----
    k_gemm1      <<<g64, blk, 0, stream>>>(x, W1, dis, A, n);
    k_gather32_g2<<<gN8, blk, 0, stream>>>(A, es, offsets, dis, b1, W2, B, n);

    // ---- layer 2 aggregation (+ fused layer-3 transform) ----
    k_gather32_dot<<<gN8, blk, 0, stream>>>(B, es, offsets, dis, b2, W3, Cs, n);

    // ---- layer 3 aggregation ----
    k_gather1<<<gN, blk, 0, stream>>>(Cs, es, offsets, dis, b3, out, n);
}

// Round 13
// 279.564 us; speedup vs baseline: 1.0759x; 1.0759x over previous
//
#include <hip/hip_runtime.h>
#include <hip/hip_fp16.h>
#include <math.h>

#define F_IN 128
#define HID  32

#define NPB   586      // nodes per bucket = ceil(150000/256) -> exactly 256 buckets
#define NBK   256      // bucket count == CU count
#define EPB   9376     // edges per block; 256 blocks (round-11 proven config)
#define CAP   12288    // fixed tmp capacity per bucket (mean 9375, +30 sigma)
#define BLK_E 1024     // threads per block for CSR kernels

#define XPAD  132      // 128 + 4: 16B-aligned row stride, conflict-free b128 reads

__device__ __forceinline__ void fma4(float4& a, float s, const float4& w) {
    a.x = fmaf(s, w.x, a.x);
    a.y = fmaf(s, w.y, a.y);
    a.z = fmaf(s, w.z, a.z);
    a.w = fmaf(s, w.w, a.w);
}

__device__ __forceinline__ void add4(float4& a, const float4& v) {
    a.x += v.x; a.y += v.y; a.z += v.z; a.w += v.w;
}

__device__ __forceinline__ float4 shx4(float4 v, int m) {
    float4 r;
    r.x = __shfl_xor(v.x, m);
    r.y = __shfl_xor(v.y, m);
    r.z = __shfl_xor(v.z, m);
    r.w = __shfl_xor(v.w, m);
    return r;
}

// fp16 quad load/store: 8B per lane, fp32 math everywhere else.
__device__ __forceinline__ float4 ldh4(const __half* p) {
    uint2 u = *(const uint2*)p;
    __half2 h0 = *(__half2*)&u.x;
    __half2 h1 = *(__half2*)&u.y;
    float2 f0 = __half22float2(h0);
    float2 f1 = __half22float2(h1);
    return make_float4(f0.x, f0.y, f1.x, f1.y);
}
__device__ __forceinline__ void sth4(__half* p, float4 v) {
    __half2 h0 = __floats2half2_rn(v.x, v.y);
    __half2 h1 = __floats2half2_rn(v.z, v.w);
    uint2 u;
    u.x = *(unsigned*)&h0;
    u.y = *(unsigned*)&h1;
    *(uint2*)p = u;
}

// ================= binned CSR build =================
// Round-13: single-pass partition. Fixed-capacity bucket slots in tmp
// (b*CAP + claim) remove the need for a global bucket prefix before the
// scatter -> the separate bhist kernel, the hb round-trip, the global
// bin_hist atomics and bpart's 1024-wide scan are all deleted. One fused
// kernel: local hist (dst) -> per-bucket claim (atomicAdd bin_cur) ->
// scatter (src+dst, dst L2-warm: 37.5KB/block). bcsr scans the final
// bucket counts (bin_cur) for es offsets and reads tmp[b*CAP..].
// 256 blocks (round-12 showed 512 regresses: fixed-overhead-bound).

#define BP_ONE(S, D) { \
    int b_ = (D) / NPB; int dl_ = (D) - b_ * NPB; \
    int r_ = atomicAdd(&lc[b_], 1); \
    tmp[h[b_] + r_] = (unsigned)(S) | ((unsigned)dl_ << 18); }

__global__ __launch_bounds__(BLK_E) void k_bpart(const int* __restrict__ src,
                                                 const int* __restrict__ dst,
                                                 int* __restrict__ bin_cur,
                                                 unsigned* __restrict__ tmp,
                                                 int e) {
    __shared__ int h[NBK];
    __shared__ int lc[NBK];
    int t = threadIdx.x;
    if (t < NBK) h[t] = 0;
    __syncthreads();
    int base = blockIdx.x * EPB;
    bool full = (base + EPB <= e);
    // ---- phase 1: block-local histogram ----
    if (full) {
        const int4* d4 = (const int4*)(dst + base);
        for (int i = t; i < EPB / 4; i += BLK_E) {
            int4 v = d4[i];
            atomicAdd(&h[v.x / NPB], 1);
            atomicAdd(&h[v.y / NPB], 1);
            atomicAdd(&h[v.z / NPB], 1);
            atomicAdd(&h[v.w / NPB], 1);
        }
    } else {
        for (int i = base + t; i < e; i += BLK_E)
            atomicAdd(&h[dst[i] / NPB], 1);
    }
    __syncthreads();
    // ---- claim: absolute slot base per bucket (no global prefix!) ----
    if (t < NBK) {
        int c = h[t];
        int r = c ? atomicAdd(&bin_cur[t], c) : 0;
        h[t] = t * CAP + r;
        lc[t] = 0;
    }
    __syncthreads();
    // ---- phase 2: scatter (dst re-read is L2-warm) ----
    if (full) {
        const int4* s4 = (const int4*)(src + base);
        const int4* d4 = (const int4*)(dst + base);
        for (int i = t; i < EPB / 4; i += BLK_E) {
            int4 sv = s4[i];
            int4 dv = d4[i];
            BP_ONE(sv.x, dv.x)
            BP_ONE(sv.y, dv.y)
            BP_ONE(sv.z, dv.z)
            BP_ONE(sv.w, dv.w)
        }
    } else {
        for (int i = base + t; i < e; i += BLK_E) {
            int d = dst[i];
            BP_ONE(src[i], d)
        }
    }
}
#undef BP_ONE

__global__ __launch_bounds__(BLK_E) void k_bcsr(const unsigned* __restrict__ tmp,
                                                const int* __restrict__ bcnt,
                                                int* __restrict__ es,
                                                int* __restrict__ offsets,
                                                float* __restrict__ dis,
                                                int n, int nbuckets, int e) {
    __shared__ int sh[BLK_E];
    __shared__ int cnt[NPB];
    __shared__ int cur[NPB];
    __shared__ int sb[2];
    int b = blockIdx.x, t = threadIdx.x;
    // scan of final bucket counts -> this bucket's output offset s0
    int hv = (t < nbuckets) ? bcnt[t] : 0;
    if (t < NPB) cnt[t] = 0;
    sh[t] = hv; __syncthreads();
    for (int off = 1; off < BLK_E; off <<= 1) {
        int a = (t >= off) ? sh[t - off] : 0;
        __syncthreads();
        sh[t] += a;
        __syncthreads();
    }
    if (t == b) { sb[0] = sh[t] - hv; sb[1] = hv; }   // s0, count
    if (b == nbuckets - 1 && t == 0) offsets[n] = e;
    __syncthreads();
    int s0 = sb[0], cb = sb[1];
    const unsigned* tb = tmp + (size_t)b * CAP;       // 16B-aligned slot base
    // count pass (uint4 vector + tail; slot base already aligned)
    int nv = cb >> 2;
    const uint4* tb4 = (const uint4*)tb;
    for (int i = t; i < nv; i += BLK_E) {
        uint4 w = tb4[i];
        atomicAdd(&cnt[(w.x >> 18) & 1023], 1);
        atomicAdd(&cnt[(w.y >> 18) & 1023], 1);
        atomicAdd(&cnt[(w.z >> 18) & 1023], 1);
        atomicAdd(&cnt[(w.w >> 18) & 1023], 1);
    }
    for (int i = (nv << 2) + t; i < cb; i += BLK_E)
        atomicAdd(&cnt[(tb[i] >> 18) & 1023], 1);
    __syncthreads();
    // node prefix within the bucket
    int v = (t < NPB) ? cnt[t] : 0;
    sh[t] = v; __syncthreads();
    for (int off = 1; off < BLK_E; off <<= 1) {
        int a = (t >= off) ? sh[t - off] : 0;
        __syncthreads();
        sh[t] += a;
        __syncthreads();
    }
    if (t < NPB) {
        int excl = sh[t] - v;
        int node = b * NPB + t;
        if (node < n) {
            offsets[node] = s0 + excl;
            dis[node] = rsqrtf((float)(v + 1));
        }
        cur[t] = excl;
    }
    __syncthreads();
    // scatter pass (uint4 vector + tail)
    for (int i = t; i < nv; i += BLK_E) {
        uint4 w = tb4[i];
        int d0 = (w.x >> 18) & 1023; int r0 = atomicAdd(&cur[d0], 1);
        es[s0 + r0] = (int)(w.x & 0x3FFFFu);
        int d1 = (w.y >> 18) & 1023; int r1 = atomicAdd(&cur[d1], 1);
        es[s0 + r1] = (int)(w.y & 0x3FFFFu);
        int d2 = (w.z >> 18) & 1023; int r2 = atomicAdd(&cur[d2], 1);
        es[s0 + r2] = (int)(w.z & 0x3FFFFu);
        int d3 = (w.w >> 18) & 1023; int r3 = atomicAdd(&cur[d3], 1);
        es[s0 + r3] = (int)(w.w & 0x3FFFFu);
    }
    for (int i = (nv << 2) + t; i < cb; i += BLK_E) {
        unsigned w = tb[i];
        int dl = (w >> 18) & 1023;
        int r = atomicAdd(&cur[dl], 1);
        es[s0 + r] = (int)(w & 0x3FFFFu);
    }
}

// ================= transforms =================

// k_gemm1: x-tile bulk-staged in LDS (round 4); fp16 output (round 8).
__global__ __launch_bounds__(256) void k_gemm1(const float* __restrict__ x,
                                               const float* __restrict__ W,
                                               const float* __restrict__ dis,
                                               __half* __restrict__ u, int n) {
    __shared__ float Ws[F_IN * HID];   // 16 KB
    __shared__ float Xs[64 * XPAD];    // 33 KB
    int tid = threadIdx.x;
    for (int i = tid; i < F_IN * HID; i += 256) Ws[i] = W[i];
    int node0 = blockIdx.x * 64;
#pragma unroll
    for (int it = 0; it < 8; ++it) {
        int c  = it * 256 + tid;       // 2048 chunks of 16B
        int r  = c >> 5;               // 32 chunks per row
        int c4 = c & 31;
        int gr = node0 + r;
        if (gr >= n) gr = n - 1;       // in-bounds junk; outputs guarded
        float4 v = *(const float4*)&x[(size_t)gr * F_IN + c4 * 4];
        *(float4*)&Xs[r * XPAD + c4 * 4] = v;
    }
    int cg = tid & 7, gq = tid >> 3;
    float4 acc[2];
    acc[0] = make_float4(0.f, 0.f, 0.f, 0.f);
    acc[1] = make_float4(0.f, 0.f, 0.f, 0.f);
    __syncthreads();
#pragma unroll 4
    for (int ks = 0; ks < 32; ++ks) {
        float4 xv[2];
        xv[0] = *(const float4*)&Xs[gq * XPAD + ks * 4];
        xv[1] = *(const float4*)&Xs[(gq + 32) * XPAD + ks * 4];
        float4 w0 = *(const float4*)&Ws[(ks * 4 + 0) * HID + cg * 4];
        float4 w1 = *(const float4*)&Ws[(ks * 4 + 1) * HID + cg * 4];
        float4 w2 = *(const float4*)&Ws[(ks * 4 + 2) * HID + cg * 4];
        float4 w3 = *(const float4*)&Ws[(ks * 4 + 3) * HID + cg * 4];
#pragma unroll
        for (int m = 0; m < 2; ++m) {
            fma4(acc[m], xv[m].x, w0);
            fma4(acc[m], xv[m].y, w1);
            fma4(acc[m], xv[m].z, w2);
            fma4(acc[m], xv[m].w, w3);
        }
    }
#pragma unroll
    for (int m = 0; m < 2; ++m) {
        int node = node0 + gq + 32 * m;
        if (node < n) {
            float ds = dis[node];
            float4 r;
            r.x = acc[m].x * ds; r.y = acc[m].y * ds;
            r.z = acc[m].z * ds; r.w = acc[m].w * ds;
            sth4(&u[(size_t)node * HID + cg * 4], r);
        }
    }
}

// ================= gather aggregation =================
// Regime (rounds 5/7): per-CU outstanding-miss bound. fp16 node rows =
// one line per edge (round 8: confirmed). gemm2 fused via 8-lane
// butterfly allgather + LDS W2 matmul (round 7).

__global__ __launch_bounds__(256) void k_gather32_g2(const __half* __restrict__ uh,
                                                     const int* __restrict__ es,
                                                     const int* __restrict__ offsets,
                                                     const float* __restrict__ dis,
                                                     const float* __restrict__ b,
                                                     const float* __restrict__ W2,
                                                     __half* __restrict__ u2, int n) {
    __shared__ float Ws[HID * HID];   // 4 KB
    int tid = threadIdx.x;
    for (int i = tid; i < HID * HID; i += 256) Ws[i] = W2[i];
    __syncthreads();
    int t = blockIdx.x * 256 + tid;
    int node = t >> 3, q = t & 7;
    if (node >= n) return;
    int s0 = offsets[node];
    int s1 = offsets[node + 1];
    float4 acc = ldh4(&uh[(size_t)node * HID + q * 4]);   // self-loop
    int ei = s0;
    for (; ei + 8 <= s1; ei += 8) {
        int e0 = es[ei], e1 = es[ei + 1], e2 = es[ei + 2], e3 = es[ei + 3];
        int e4 = es[ei + 4], e5 = es[ei + 5], e6 = es[ei + 6], e7 = es[ei + 7];
        float4 v0 = ldh4(&uh[(size_t)e0 * HID + q * 4]);
        float4 v1 = ldh4(&uh[(size_t)e1 * HID + q * 4]);
        float4 v2 = ldh4(&uh[(size_t)e2 * HID + q * 4]);
        float4 v3 = ldh4(&uh[(size_t)e3 * HID + q * 4]);
        float4 v4 = ldh4(&uh[(size_t)e4 * HID + q * 4]);
        float4 v5 = ldh4(&uh[(size_t)e5 * HID + q * 4]);
        float4 v6 = ldh4(&uh[(size_t)e6 * HID + q * 4]);
        float4 v7 = ldh4(&uh[(size_t)e7 * HID + q * 4]);
        acc.x += ((v0.x + v1.x) + (v2.x + v3.x)) + ((v4.x + v5.x) + (v6.x + v7.x));
        acc.y += ((v0.y + v1.y) + (v2.y + v3.y)) + ((v4.y + v5.y) + (v6.y + v7.y));
        acc.z += ((v0.z + v1.z) + (v2.z + v3.z)) + ((v4.z + v5.z) + (v6.z + v7.z));
        acc.w += ((v0.w + v1.w) + (v2.w + v3.w)) + ((v4.w + v5.w) + (v6.w + v7.w));
    }
    for (; ei + 4 <= s1; ei += 4) {
        int e0 = es[ei], e1 = es[ei + 1], e2 = es[ei + 2], e3 = es[ei + 3];
        float4 v0 = ldh4(&uh[(size_t)e0 * HID + q * 4]);
        float4 v1 = ldh4(&uh[(size_t)e1 * HID + q * 4]);
        float4 v2 = ldh4(&uh[(size_t)e2 * HID + q * 4]);
        float4 v3 = ldh4(&uh[(size_t)e3 * HID + q * 4]);
        acc.x += (v0.x + v1.x) + (v2.x + v3.x);
        acc.y += (v0.y + v1.y) + (v2.y + v3.y);
        acc.z += (v0.z + v1.z) + (v2.z + v3.z);
        acc.w += (v0.w + v1.w) + (v2.w + v3.w);
    }
    for (; ei < s1; ++ei) {
        int s = es[ei];
        float4 v = ldh4(&uh[(size_t)s * HID + q * 4]);
        add4(acc, v);
    }
    float ds = dis[node];
    float4 r;   // h quad, k-range [q*4, q*4+4)
    r.x = fmaxf(fmaf(ds, acc.x, b[q * 4 + 0]), 0.0f);
    r.y = fmaxf(fmaf(ds, acc.y, b[q * 4 + 1]), 0.0f);
    r.z = fmaxf(fmaf(ds, acc.z, b[q * 4 + 2]), 0.0f);
    r.w = fmaxf(fmaf(ds, acc.w, b[q * 4 + 3]), 0.0f);

    // --- butterfly allgather: H0..H7 = full h row in every lane ---
    float4 o1 = shx4(r, 1);
    float4 L0 = (q & 1) ? o1 : r;
    float4 L1 = (q & 1) ? r  : o1;
    float4 M0 = shx4(L0, 2);
    float4 M1 = shx4(L1, 2);
    float4 P0 = (q & 2) ? M0 : L0;
    float4 P1 = (q & 2) ? M1 : L1;
    float4 P2 = (q & 2) ? L0 : M0;
    float4 P3 = (q & 2) ? L1 : M1;
    float4 Q0 = shx4(P0, 4);
    float4 Q1 = shx4(P1, 4);
    float4 Q2 = shx4(P2, 4);
    float4 Q3 = shx4(P3, 4);
    float4 H0 = (q & 4) ? Q0 : P0;
    float4 H1 = (q & 4) ? Q1 : P1;
    float4 H2 = (q & 4) ? Q2 : P2;
    float4 H3 = (q & 4) ? Q3 : P3;
    float4 H4 = (q & 4) ? P0 : Q0;
    float4 H5 = (q & 4) ? P1 : Q1;
    float4 H6 = (q & 4) ? P2 : Q2;
    float4 H7 = (q & 4) ? P3 : Q3;

    // --- u2 quad q = (h @ W2)[q*4 .. q*4+3], scaled by ds ---
    float4 oacc = make_float4(0.f, 0.f, 0.f, 0.f);
#define G2_STEP(Hj, j) { \
    float4 w0 = *(const float4*)&Ws[((j) * 4 + 0) * HID + q * 4]; \
    float4 w1 = *(const float4*)&Ws[((j) * 4 + 1) * HID + q * 4]; \
    float4 w2 = *(const float4*)&Ws[((j) * 4 + 2) * HID + q * 4]; \
    float4 w3 = *(const float4*)&Ws[((j) * 4 + 3) * HID + q * 4]; \
    fma4(oacc, Hj.x, w0); fma4(oacc, Hj.y, w1); \
    fma4(oacc, Hj.z, w2); fma4(oacc, Hj.w, w3); }
    G2_STEP(H0, 0) G2_STEP(H1, 1) G2_STEP(H2, 2) G2_STEP(H3, 3)
    G2_STEP(H4, 4) G2_STEP(H5, 5) G2_STEP(H6, 6) G2_STEP(H7, 7)
#undef G2_STEP
    float4 w;
    w.x = oacc.x * ds; w.y = oacc.y * ds;
    w.z = oacc.z * ds; w.w = oacc.w * ds;
    sth4(&u2[(size_t)node * HID + q * 4], w);
}

__global__ __launch_bounds__(256) void k_gather32_dot(const __half* __restrict__ uh,
                                                      const int* __restrict__ es,
                                                      const int* __restrict__ offsets,
                                                      const float* __restrict__ dis,
                                                      const float* __restrict__ b,
                                                      const float* __restrict__ W3,
                                                      float* __restrict__ s, int n) {
    int t = blockIdx.x * 256 + threadIdx.x;
    int node = t >> 3, q = t & 7;
    if (node >= n) return;
    int s0 = offsets[node];
    int s1 = offsets[node + 1];
    float4 acc = ldh4(&uh[(size_t)node * HID + q * 4]);
    int ei = s0;
    for (; ei + 8 <= s1; ei += 8) {
        int e0 = es[ei], e1 = es[ei + 1], e2 = es[ei + 2], e3 = es[ei + 3];
        int e4 = es[ei + 4], e5 = es[ei + 5], e6 = es[ei + 6], e7 = es[ei + 7];
        float4 v0 = ldh4(&uh[(size_t)e0 * HID + q * 4]);
        float4 v1 = ldh4(&uh[(size_t)e1 * HID + q * 4]);
        float4 v2 = ldh4(&uh[(size_t)e2 * HID + q * 4]);
        float4 v3 = ldh4(&uh[(size_t)e3 * HID + q * 4]);
        float4 v4 = ldh4(&uh[(size_t)e4 * HID + q * 4]);
        float4 v5 = ldh4(&uh[(size_t)e5 * HID + q * 4]);
        float4 v6 = ldh4(&uh[(size_t)e6 * HID + q * 4]);
        float4 v7 = ldh4(&uh[(size_t)e7 * HID + q * 4]);
        acc.x += ((v0.x + v1.x) + (v2.x + v3.x)) + ((v4.x + v5.x) + (v6.x + v7.x));
        acc.y += ((v0.y + v1.y) + (v2.y + v3.y)) + ((v4.y + v5.y) + (v6.y + v7.y));
        acc.z += ((v0.z + v1.z) + (v2.z + v3.z)) + ((v4.z + v5.z) + (v6.z + v7.z));
        acc.w += ((v0.w + v1.w) + (v2.w + v3.w)) + ((v4.w + v5.w) + (v6.w + v7.w));
    }
    for (; ei + 4 <= s1; ei += 4) {
        int e0 = es[ei], e1 = es[ei + 1], e2 = es[ei + 2], e3 = es[ei + 3];
        float4 v0 = ldh4(&uh[(size_t)e0 * HID + q * 4]);
        float4 v1 = ldh4(&uh[(size_t)e1 * HID + q * 4]);
        float4 v2 = ldh4(&uh[(size_t)e2 * HID + q * 4]);
        float4 v3 = ldh4(&uh[(size_t)e3 * HID + q * 4]);
        acc.x += (v0.x + v1.x) + (v2.x + v3.x);
        acc.y += (v0.y + v1.y) + (v2.y + v3.y);
        acc.z += (v0.z + v1.z) + (v2.z + v3.z);
        acc.w += (v0.w + v1.w) + (v2.w + v3.w);
    }
    for (; ei < s1; ++ei) {
        int sc = es[ei];
        float4 v = ldh4(&uh[(size_t)sc * HID + q * 4]);
        add4(acc, v);
    }
    float ds = dis[node];
    float4 r;
    r.x = fmaxf(fmaf(ds, acc.x, b[q * 4 + 0]), 0.0f);
    r.y = fmaxf(fmaf(ds, acc.y, b[q * 4 + 1]), 0.0f);
    r.z = fmaxf(fmaf(ds, acc.z, b[q * 4 + 2]), 0.0f);
    r.w = fmaxf(fmaf(ds, acc.w, b[q * 4 + 3]), 0.0f);
    float p = r.x * W3[q * 4 + 0] + r.y * W3[q * 4 + 1]
            + r.z * W3[q * 4 + 2] + r.w * W3[q * 4 + 3];
    p += __shfl_down(p, 4, 8);
    p += __shfl_down(p, 2, 8);
    p += __shfl_down(p, 1, 8);
    if (q == 0) s[node] = p * ds;
}

__global__ void k_gather1(const float* __restrict__ sv, const int* __restrict__ es,
                          const int* __restrict__ offsets, const float* __restrict__ dis,
                          const float* __restrict__ b3, float* __restrict__ out, int n) {
    int d = blockIdx.x * 256 + threadIdx.x;
    if (d >= n) return;
    float acc = sv[d];
    int s0 = offsets[d], s1 = offsets[d + 1];
    int ei = s0;
    for (; ei + 4 <= s1; ei += 4) {
        float v0 = sv[es[ei]], v1 = sv[es[ei + 1]];
        float v2 = sv[es[ei + 2]], v3 = sv[es[ei + 3]];
        acc += (v0 + v1) + (v2 + v3);
    }
    for (; ei < s1; ++ei) acc += sv[es[ei]];
    float z = dis[d] * acc + b3[0];
    out[d] = 1.0f / (1.0f + expf(-z));
}

// ================= launch =================

extern "C" void kernel_launch(void* const* d_in, const int* in_sizes, int n_in,
                              void* d_out, int out_size, void* d_ws, size_t ws_size,
                              hipStream_t stream) {
    const float* x  = (const float*)d_in[0];
    const int*   ei = (const int*)d_in[1];
    const float* W1 = (const float*)d_in[2];
    const float* b1 = (const float*)d_in[3];
    const float* W2 = (const float*)d_in[4];
    const float* b2 = (const float*)d_in[5];
    const float* W3 = (const float*)d_in[6];
    const float* b3 = (const float*)d_in[7];
    float* out = (float*)d_out;

    int n = out_size;             // 150000
    int e = in_sizes[1] / 2;      // 2400000
    const int* src = ei;
    const int* dst = ei + e;

    int nbuckets = (n + NPB - 1) / NPB;   // 256
    int gEb      = (e + EPB - 1) / EPB;   // 256

    __half* A       = (__half*)d_ws;                // n*32 halfs (9.6MB)
    __half* B       = A + (size_t)n * HID;          // n*32 halfs (9.6MB)
    float* dis      = (float*)(B + (size_t)n * HID);// n f
    float* Cs       = dis + n;                      // n f
    int*   offsets  = (int*)(Cs + n);               // n+1 i
    int*   es       = offsets + (n + 1);            // e i
    int*   bin_cur  = es + e;                       // nbuckets i
    unsigned* tmp   = (unsigned*)A;                 // NBK*CAP u32 = 12.6MB,
                                                    // aliases A + head of B
                                                    // (both dead during CSR build;
                                                    // gemm1/g2 write them after)

    dim3 blk(256);
    int gN    = (n + 255) / 256;
    int gN8   = (n * 8 + 255) / 256;
    int g64   = (n + 63) / 64;         // 2344

    // ---- CSR build: fused partition + bucket CSR (2 dispatches) ----
    hipMemsetAsync(bin_cur, 0, (size_t)nbuckets * sizeof(int), stream);
    k_bpart<<<gEb, dim3(BLK_E), 0, stream>>>(src, dst, bin_cur, tmp, e);
    k_bcsr <<<nbuckets, dim3(BLK_E), 0, stream>>>(tmp, bin_cur, es, offsets, dis, n, nbuckets, e);

    // ---- layer 1 (+ fused layer-2 transform) ----
    k_gemm1      <<<g64, blk, 0, stream>>>(x, W1, dis, A, n);
    k_gather32_g2<<<gN8, blk, 0, stream>>>(A, es, offsets, dis, b1, W2, B, n);

    // ---- layer 2 aggregation (+ fused layer-3 transform) ----
    k_gather32_dot<<<gN8, blk, 0, stream>>>(B, es, offsets, dis, b2, W3, Cs, n);

    // ---- layer 3 aggregation ----
    k_gather1<<<gN, blk, 0, stream>>>(Cs, es, offsets, dis, b3, out, n);
}